// Round 12
// baseline (682.281 us; speedup 1.0000x reference)
//
#include <hip/hip_runtime.h>
#include <stdint.h>

typedef unsigned short u16;
typedef __attribute__((ext_vector_type(8))) short short8;
typedef __attribute__((ext_vector_type(4))) short short4v;
typedef __attribute__((ext_vector_type(4))) float floatx4;

#define T_DIM 2048
#define NH    16
#define HD    128
#define H_DIM 2048
#define I_DIM 8192
#define NCOL1 22528   // 3H + 2I
#define NCOL2 10240   // H + I
#define KSPLIT 4
#define KSLEN  (NCOL2 / KSPLIT)   // 2560

#define VMBAR(n) asm volatile("s_waitcnt vmcnt(" #n ")\n\ts_barrier" ::: "memory")

__device__ __forceinline__ float bf2f(u16 b) {
  union { uint32_t u; float f; } x; x.u = ((uint32_t)b) << 16; return x.f;
}
__device__ __forceinline__ u16 f2bf(float f) {
  union { float f; uint32_t u; } x; x.f = f;
  uint32_t r = x.u + 0x7fffu + ((x.u >> 16) & 1u);
  return (u16)(r >> 16);
}

__device__ __forceinline__ void gl_lds16(const void* g, void* l) {
  __builtin_amdgcn_global_load_lds((const __attribute__((address_space(1))) void*)g,
                                   (__attribute__((address_space(3))) void*)l, 16, 0, 0);
}

__device__ __forceinline__ floatx4 mfma32(short8 a, short8 b, floatx4 c) {
  return __builtin_amdgcn_mfma_f32_16x16x32_bf16(a, b, c, 0, 0, 0);
}
__device__ __forceinline__ floatx4 mfma16(short4v a, short4v b, floatx4 c) {
#if __has_builtin(__builtin_amdgcn_mfma_f32_16x16x16bf16_1k)
  return __builtin_amdgcn_mfma_f32_16x16x16bf16_1k(a, b, c, 0, 0, 0);
#else
  asm volatile("v_mfma_f32_16x16x16_bf16 %0, %1, %2, %0" : "+v"(c) : "v"(a), "v"(b));
  return c;
#endif
}

// ---------------- RMSNorm + age override -> bf16 ----------------
__global__ __launch_bounds__(256) void rmsnorm_k(
    const float* __restrict__ x, const float* __restrict__ ages,
    const float* __restrict__ w, u16* __restrict__ xn) {
  int t = blockIdx.x, tid = threadIdx.x;
  const float* xr = x + (size_t)t * H_DIM;
  floatx4 a = *(const floatx4*)(xr + tid * 8);
  floatx4 b = *(const floatx4*)(xr + tid * 8 + 4);
  float ss = a[0]*a[0]+a[1]*a[1]+a[2]*a[2]+a[3]*a[3]
           + b[0]*b[0]+b[1]*b[1]+b[2]*b[2]+b[3]*b[3];
#pragma unroll
  for (int off = 32; off >= 1; off >>= 1) ss += __shfl_xor(ss, off);
  __shared__ float red[4];
  if ((tid & 63) == 0) red[tid >> 6] = ss;
  __syncthreads();
  float tot = red[0] + red[1] + red[2] + red[3];
  float rms = rsqrtf(tot * (1.0f / H_DIM) + 1e-6f);
  const float* wr = w + tid * 8;
  float v[8] = {a[0],a[1],a[2],a[3],b[0],b[1],b[2],b[3]};
  short8 o;
#pragma unroll
  for (int i = 0; i < 8; ++i) o[i] = (short)f2bf(v[i] * rms * wr[i]);
  if (tid == 255) {           // covers cols 2040..2047
    float ag = ages[t];
    o[6] = (short)f2bf(ag);
    o[7] = (short)f2bf(ag * ag);
  }
  *(short8*)(xn + (size_t)t * H_DIM + tid * 8) = o;
}

// ------------- fp32 (K,N) -> bf16 (N,K) transpose ---------------
__global__ __launch_bounds__(256) void transpose_f32_bf16(
    const float* __restrict__ in, u16* __restrict__ out, int K, int N) {
  __shared__ float tile[32][33];
  int n0 = blockIdx.x * 32, k0 = blockIdx.y * 32;
  int c = threadIdx.x & 31, r = threadIdx.x >> 5;
#pragma unroll
  for (int i = 0; i < 4; ++i) {
    int kk = r + i * 8;
    tile[c][kk] = in[(size_t)(k0 + kk) * N + n0 + c];
  }
  __syncthreads();
#pragma unroll
  for (int i = 0; i < 4; ++i) {
    int nn = r + i * 8;
    out[(size_t)(n0 + nn) * K + k0 + c] = f2bf(tile[nn][c]);
  }
}

// ---- bf16 GEMM, B^T (N-major), 256x256 tile, 8 waves, ring-4 (R8) --------
// Single-phase per K-tile: 12 ds_read + stage(t+3) + 32 MFMA, boundary
// vmcnt(8)+barrier (counted, never drains the in-flight prefetch).
// Swizzle: phys k16 = lg ^ ((lq>>1)&3); staging pre-swizzles global source.
// OUTF: 0 bf16+bias, 1 f32+bias, 2 f32 split-K partial (at Cout + sp*M*N).
template<int OUTF>
__global__ __launch_bounds__(512, 2) void gemm256(
    const u16* __restrict__ A, const u16* __restrict__ B,
    const float* __restrict__ bias, void* __restrict__ Cout,
    int M, int N, int K, int klen) {
  __shared__ __align__(16) u16 sm[65536];   // 4 slots x (A 8192 + B 8192) u16
  int nbm = M >> 8, nbn = N >> 8;
  int per = nbm * nbn;
  int nwg = per * (K / klen);
  int bid = blockIdx.x;
  int swz = (bid & 7) * (nwg >> 3) + (bid >> 3);   // XCD swizzle (nwg%8==0)
  int sp = swz / per, rr = swz % per;
  int bn = rr / nbm, bm = rr % nbm;                // bn-major (B-panel reuse)
  int kbeg = sp * klen;
  int tid = threadIdx.x, lane = tid & 63;
  int wid = tid >> 6;            // 0..7
  int wrow = wid >> 2;           // 0..1 (M half)
  int wcol = wid & 3;            // 0..3 (N quarter)
  int lq = lane & 15, lg = lane >> 4;

  // staging: thread tid covers rows (tid>>2) and 128+(tid>>2); 16B each.
  int srow = tid >> 2;
  int scol = ((tid & 3) ^ ((tid >> 3) & 3)) << 3;   // pre-swizzled src col (u16)
  const u16* Ag0 = A + (size_t)(bm * 256 + srow) * K + kbeg + scol;
  const u16* Ag1 = Ag0 + (size_t)128 * K;
  const u16* Bg0 = B + (size_t)(bn * 256 + srow) * K + kbeg + scol;
  const u16* Bg1 = Bg0 + (size_t)128 * K;
  u16* Ad0 = sm + tid * 8;           // linear LDS dest; addr(row,k16)=row*32+k16*8
  u16* Ad1 = sm + 4096 + tid * 8;
  u16* Bd0 = sm + 8192 + tid * 8;
  u16* Bd1 = sm + 12288 + tid * 8;

  // frag read offsets (physical = logical k16 XOR ((lq>>1)&3))
  int xorc = ((lq >> 1) & 3) << 3;
  int aoff = (wrow * 128 + lq) * 32 + ((lg * 8) ^ xorc);
  int boff = 8192 + (wcol * 64 + lq) * 32 + ((lg * 8) ^ xorc);

  floatx4 acc[8][4] = {};
  const int NT = klen >> 5;

  auto STAGE = [&](int t) {
    int sl = (t & 3) * 16384;
    int ko = t * 32;
    gl_lds16(Ag0 + ko, Ad0 + sl);
    gl_lds16(Ag1 + ko, Ad1 + sl);
    gl_lds16(Bg0 + ko, Bd0 + sl);
    gl_lds16(Bg1 + ko, Bd1 + sl);
  };

  STAGE(0); STAGE(1); STAGE(2);
  VMBAR(8);   // tile 0 resident

  for (int t = 0; t < NT; ++t) {
    if (t + 3 < NT) STAGE(t + 3);
    const u16* sb = sm + (t & 3) * 16384;
    short8 af[8], bfr[4];
#pragma unroll
    for (int i = 0; i < 8; ++i) af[i]  = *(const short8*)(sb + aoff + i * 512);
#pragma unroll
    for (int i = 0; i < 4; ++i) bfr[i] = *(const short8*)(sb + boff + i * 512);
    __builtin_amdgcn_s_setprio(1);
#pragma unroll
    for (int mi = 0; mi < 8; ++mi)
#pragma unroll
      for (int ni = 0; ni < 4; ++ni)
        acc[mi][ni] = mfma32(af[mi], bfr[ni], acc[mi][ni]);
    __builtin_amdgcn_s_setprio(0);
    if (t + 3 < NT) VMBAR(8);
    else            VMBAR(0);
  }

#pragma unroll
  for (int mi = 0; mi < 8; ++mi) {
#pragma unroll
    for (int ni = 0; ni < 4; ++ni) {
      int col = bn * 256 + wcol * 64 + ni * 16 + lq;
      float bv = (OUTF == 2) ? 0.f : bias[col];
#pragma unroll
      for (int j = 0; j < 4; ++j) {
        int row = bm * 256 + wrow * 128 + mi * 16 + lg * 4 + j;
        float vv = acc[mi][ni][j] + bv;
        if (OUTF == 0)      ((u16*)Cout)[(size_t)row * N + col] = f2bf(vv);
        else if (OUTF == 1) ((float*)Cout)[(size_t)row * N + col] = vv;
        else ((float*)Cout)[(size_t)sp * M * N + (size_t)row * N + col] = vv;
      }
    }
  }
}

// ---- reduce split-K partials + bias -> f32 out ------------------
__global__ __launch_bounds__(256) void reduce_split(
    const float* __restrict__ part, const float* __restrict__ bias,
    float* __restrict__ out) {
  size_t idx = ((size_t)blockIdx.x * 256 + threadIdx.x) * 4;
  int col = (int)(idx & (H_DIM - 1));
  floatx4 acc = *(const floatx4*)(bias + col);
#pragma unroll
  for (int s = 0; s < KSPLIT; ++s) {
    floatx4 p = *(const floatx4*)(part + (size_t)s * T_DIM * H_DIM + idx);
#pragma unroll
    for (int j = 0; j < 4; ++j) acc[j] += p[j];
  }
  *(floatx4*)(out + idx) = acc;
}

// ---- RoPE on q,k; split qkv; K,V stored in MFMA-fragment order ----
__global__ __launch_bounds__(256) void rope_split(
    const u16* __restrict__ tb, const float* __restrict__ sinp, const float* __restrict__ cosp,
    u16* __restrict__ qb, u16* __restrict__ kf, u16* __restrict__ vf) {
  __shared__ u16 vtile[32][130];
  int t0 = blockIdx.x * 32, h = blockIdx.y, tid = threadIdx.x;
  int r = tid >> 3, d0 = (tid & 7) << 4;
  int t = t0 + r;
  const u16* base = tb + (size_t)t * NCOL1 + 2 * I_DIM + h * HD + d0;
  const float* cp = cosp + (size_t)t * HD + d0;
  const float* sp = sinp + (size_t)t * HD + d0;
  float cv[16], sv[16];
#pragma unroll
  for (int i = 0; i < 16; i += 4) {
    *(floatx4*)(cv + i) = *(const floatx4*)(cp + i);
    *(floatx4*)(sv + i) = *(const floatx4*)(sp + i);
  }
#pragma unroll
  for (int s = 0; s < 2; ++s) {
    const u16* src = base + s * (NH * HD);
    short8 x0 = *(const short8*)src;
    short8 x1 = *(const short8*)(src + 8);
    float xf[16];
#pragma unroll
    for (int i = 0; i < 8; ++i) { xf[i] = bf2f((u16)x0[i]); xf[8 + i] = bf2f((u16)x1[i]); }
    short8 o0, o1;
#pragma unroll
    for (int i = 0; i < 8; i += 2) {
      o0[i]     = (short)f2bf(xf[i] * cv[i] - xf[i + 1] * sv[i]);
      o0[i + 1] = (short)f2bf(xf[i + 1] * cv[i + 1] + xf[i] * sv[i + 1]);
      o1[i]     = (short)f2bf(xf[8 + i] * cv[8 + i] - xf[9 + i] * sv[8 + i]);
      o1[i + 1] = (short)f2bf(xf[9 + i] * cv[9 + i] + xf[8 + i] * sv[9 + i]);
    }
    if (s == 0) {
      u16* dst = qb + ((size_t)h * T_DIM + t) * HD + d0;
      *(short8*)dst = o0;
      *(short8*)(dst + 8) = o1;
    } else {
      int s16 = t >> 4, tt = d0 >> 5, lg0 = (d0 >> 3) & 3;
      size_t cb = (((size_t)h * 128 + s16) * 4 + tt) * 512 + ((t & 15) + 16 * lg0) * 8;
      *(short8*)(kf + cb) = o0;          // lg0
      *(short8*)(kf + cb + 128) = o1;    // lg0+1
    }
  }
  short8 v0 = *(const short8*)(base + 2 * NH * HD);
  short8 v1 = *(const short8*)(base + 2 * NH * HD + 8);
#pragma unroll
  for (int i = 0; i < 8; ++i) {
    vtile[r][d0 + i]     = (u16)v0[i];
    vtile[r][d0 + 8 + i] = (u16)v1[i];
  }
  __syncthreads();
  {
    int d = tid >> 1, th = (tid & 1) << 4;
    int s16 = (t0 + th) >> 4;
    int dp = d >> 5, par = (d >> 4) & 1, lqv = d & 15;
    size_t cb = (((size_t)h * 128 + s16) * 4 + dp) * 512 + par * 4;
#pragma unroll
    for (int lg = 0; lg < 4; ++lg) {
      short4v g;
#pragma unroll
      for (int j = 0; j < 4; ++j) g[j] = (short)vtile[th + lg * 4 + j][d];
      *(short4v*)(vf + cb + (size_t)(lqv + 16 * lg) * 8) = g;
    }
  }
}

// -------------------- silu(x1)*x2 -> comb[:, H:] -----------------
__global__ __launch_bounds__(256) void silu_mul(
    const u16* __restrict__ tb, u16* __restrict__ comb) {
  int idx = blockIdx.x * 256 + threadIdx.x;
  int t = idx >> 10;
  int j = (idx & 1023) << 3;
  const u16* p1 = tb + (size_t)t * NCOL1 + j;
  const u16* p2 = p1 + I_DIM;
  short8 a = *(const short8*)p1;
  short8 b = *(const short8*)p2;
  short8 o;
#pragma unroll
  for (int i = 0; i < 8; ++i) {
    float x1 = bf2f((u16)a[i]), x2 = bf2f((u16)b[i]);
    float s = x1 / (1.0f + __expf(-x1));
    o[i] = (short)f2bf(s * x2);
  }
  *(short8*)(comb + (size_t)t * NCOL2 + H_DIM + j) = o;
}

// ---- fused flash attention; bias dense in LDS; K/V fragment-packed ----
// R12: bias tile shrunk 1024->512 cols (4 tiles). LDS = 34KB (stage 16x516
// union merge scratch) -> 4 blocks/CU, 16 waves/CU: out-of-phase blocks hide
// each other's stage drains. Unconditional rescale (T13 regressed, R11).
__global__ __launch_bounds__(256) void attn_fused(
    const u16* __restrict__ Q, const u16* __restrict__ kf,
    const u16* __restrict__ vf, const float* __restrict__ bias,
    u16* __restrict__ comb) {
  __shared__ float lds[8576];   // stage: 16x516 f32 (8256); merge uses up to 8576
  int bid = blockIdx.x;
  int swz = (bid & 7) * 256 + (bid >> 3);   // 2048 blocks, bijective XCD swizzle
  int h = swz >> 7, qt = swz & 127;
  int q0 = qt * 16;
  int tid = threadIdx.x;
  int w = tid >> 6, lane = tid & 63;
  int lq = lane & 15, lg = lane >> 4;

  const u16* Qp = Q + ((size_t)h * T_DIM + q0 + lq) * HD + lg * 8;
  const u16* Kf = kf + ((size_t)h * 128) * 2048 + lane * 8;  // + s16*2048 + t*512
  const u16* Vf = vf + ((size_t)h * 128) * 2048 + lane * 8;  // + s16*2048 + dp*512
  const float* Bh = bias + ((size_t)h * T_DIM + q0) * T_DIM;

  short8 qf[4];
#pragma unroll
  for (int t = 0; t < 4; ++t) qf[t] = *(const short8*)(Qp + t * 32);

  floatx4 o[8] = {};
  float m = -1e30f, l = 0.f;
  const float sc = 0.08838834764831845f;   // 1/sqrt(128)

  int r2 = tid >> 7;              // staging: row parity
  int scl = (tid & 127) * 4;      // staging: col within 512

  for (int tile = 0; tile < 4; ++tile) {
    // ---- stage bias tile: 16 rows x 2KB contiguous each (8 gl_lds/thread) --
#pragma unroll
    for (int rrr = 0; rrr < 8; ++rrr) {
      int r = rrr * 2 + r2;
      const float* src = Bh + (size_t)r * T_DIM + tile * 512 + scl;
      gl_lds16(src, &lds[r * 516 + scl]);
    }
    __syncthreads();   // drains vmcnt -> tile resident
    // ---- each wave: 4 sub-bodies of 32 s, strided by 128 ----
#pragma unroll
    for (int sub = 0; sub < 4; ++sub) {
      int soff = sub * 128 + w * 32;          // offset within tile
      int s0 = tile * 512 + soff;             // global s
      int s16a = s0 >> 4;
      const u16* ka = Kf + (size_t)s16a * 2048;
      floatx4 st0 = {0.f,0.f,0.f,0.f}, st1 = {0.f,0.f,0.f,0.f};
#pragma unroll
      for (int t = 0; t < 4; ++t) {
        st0 = mfma32(*(const short8*)(ka + t * 512), qf[t], st0);
        st1 = mfma32(*(const short8*)(ka + 2048 + t * 512), qf[t], st1);
      }
      floatx4 b0 = *(const floatx4*)&lds[lq * 516 + soff + lg * 4];
      floatx4 b1 = *(const floatx4*)&lds[lq * 516 + soff + lg * 4 + 16];
      float p[8]; float tmax = -1e30f;
#pragma unroll
      for (int j = 0; j < 4; ++j) {
        p[j]     = st0[j] * sc + b0[j];
        p[4 + j] = st1[j] * sc + b1[j];
        tmax = fmaxf(tmax, fmaxf(p[j], p[4 + j]));
      }
      tmax = fmaxf(tmax, __shfl_xor(tmax, 16));
      tmax = fmaxf(tmax, __shfl_xor(tmax, 32));
      float mn = fmaxf(m, tmax);
      float alpha = __expf(m - mn);
      float rs = 0.f;
      short4v pb0, pb1;
#pragma unroll
      for (int j = 0; j < 4; ++j) {
        float e0 = __expf(p[j] - mn), e1 = __expf(p[4 + j] - mn);
        rs += e0 + e1;
        pb0[j] = (short)f2bf(e0);
        pb1[j] = (short)f2bf(e1);
      }
      rs += __shfl_xor(rs, 16);
      rs += __shfl_xor(rs, 32);
      l = l * alpha + rs; m = mn;
#pragma unroll
      for (int dt = 0; dt < 8; ++dt) o[dt] *= alpha;
      const u16* vb = Vf + (size_t)s16a * 2048;
#pragma unroll
      for (int dp = 0; dp < 4; ++dp) {
        short8 wa = *(const short8*)(vb + dp * 512);
        short8 wb = *(const short8*)(vb + 2048 + dp * 512);
        short4v a0 = {wa[0], wa[1], wa[2], wa[3]};
        short4v a1 = {wa[4], wa[5], wa[6], wa[7]};
        short4v c0 = {wb[0], wb[1], wb[2], wb[3]};
        short4v c1 = {wb[4], wb[5], wb[6], wb[7]};
        o[2*dp]     = mfma16(a0, pb0, o[2*dp]);
        o[2*dp + 1] = mfma16(a1, pb0, o[2*dp + 1]);
        o[2*dp]     = mfma16(c0, pb1, o[2*dp]);
        o[2*dp + 1] = mfma16(c1, pb1, o[2*dp + 1]);
      }
    }
    __syncthreads();   // all waves done reading before restage/merge
  }

  // ---- in-block 4-way (m,l,o) merge via LDS ----
  if (lg == 0) { lds[8448 + w * 16 + lq] = m; lds[8512 + w * 16 + lq] = l; }
  __syncthreads();
  float M = -1e30f;
#pragma unroll
  for (int i = 0; i < 4; ++i) M = fmaxf(M, lds[8448 + i * 16 + lq]);
  float scale = __expf(m - M);
#pragma unroll
  for (int dt = 0; dt < 8; ++dt) {
    floatx4 so = o[dt] * scale;
    *(floatx4*)&lds[w * 2112 + lq * 132 + dt * 16 + lg * 4] = so;
  }
  __syncthreads();
  // final reduce + normalize + write: thread t -> row t>>4, d0 = (t&15)*8
  {
    int row = tid >> 4, d0 = (tid & 15) * 8;
    float M2 = -1e30f;
#pragma unroll
    for (int i = 0; i < 4; ++i) M2 = fmaxf(M2, lds[8448 + i * 16 + row]);
    float den = 0.f;
#pragma unroll
    for (int i = 0; i < 4; ++i)
      den += __expf(lds[8448 + i * 16 + row] - M2) * lds[8512 + i * 16 + row];
    float inv = 1.0f / den;
    short8 ov;
#pragma unroll
    for (int k = 0; k < 8; ++k) {
      float s = 0.f;
#pragma unroll
      for (int i = 0; i < 4; ++i) s += lds[i * 2112 + row * 132 + d0 + k];
      ov[k] = (short)f2bf(s * inv);
    }
    *(short8*)(comb + (size_t)(q0 + row) * NCOL2 + h * HD + d0) = ov;
  }
}

extern "C" void kernel_launch(void* const* d_in, const int* in_sizes, int n_in,
                              void* d_out, int out_size, void* d_ws, size_t ws_size,
                              hipStream_t stream) {
  (void)in_sizes; (void)n_in; (void)out_size; (void)ws_size;
  const float* x     = (const float*)d_in[0];
  const float* ages  = (const float*)d_in[1];
  const float* sinp  = (const float*)d_in[2];
  const float* cosp  = (const float*)d_in[3];
  const float* bias  = (const float*)d_in[4];
  const float* normw = (const float*)d_in[5];
  const float* w_in  = (const float*)d_in[6];
  const float* b_in  = (const float*)d_in[7];
  const float* w_out = (const float*)d_in[8];
  const float* b_out = (const float*)d_in[9];

  char* ws = (char*)d_ws;
  const size_t SZ_XN   = (size_t)T_DIM * H_DIM * 2;      //  8 MiB
  const size_t SZ_W1T  = (size_t)NCOL1 * H_DIM * 2;      //  88 MiB
  const size_t SZ_T    = (size_t)T_DIM * NCOL1 * 2;      //  88 MiB
  const size_t SZ_HEAD = (size_t)NH * T_DIM * HD * 2;    //   8 MiB
  u16* xn   = (u16*)(ws);
  u16* w1t  = (u16*)(ws + SZ_XN);
  u16* tb   = (u16*)(ws + SZ_XN + SZ_W1T);
  u16* qb   = (u16*)(ws + SZ_XN + SZ_W1T + SZ_T);
  u16* kf   = (u16*)(ws + SZ_XN + SZ_W1T + SZ_T + SZ_HEAD);
  u16* vf   = (u16*)(ws + SZ_XN + SZ_W1T + SZ_T + 2 * SZ_HEAD);
  u16* w2t  = (u16*)(ws + SZ_XN);                  // reuse w1t region (dead after GEMM1)
  u16* comb = (u16*)(ws + SZ_XN + (48ull << 20));  // also inside w1t region, disjoint from w2t
  float* part = (float*)tb;                        // split-K partials (64 MiB) in dead tb region

  rmsnorm_k<<<T_DIM, 256, 0, stream>>>(x, ages, normw, xn);
  transpose_f32_bf16<<<dim3(NCOL1 / 32, H_DIM / 32), 256, 0, stream>>>(w_in, w1t, H_DIM, NCOL1);
  gemm256<0><<<(T_DIM / 256) * (NCOL1 / 256), 512, 0, stream>>>(
      xn, w1t, b_in, tb, T_DIM, NCOL1, H_DIM, H_DIM);
  rope_split<<<dim3(T_DIM / 32, NH), 256, 0, stream>>>(tb, sinp, cosp, qb, kf, vf);
  silu_mul<<<(T_DIM * I_DIM) / (256 * 8), 256, 0, stream>>>(tb, comb);
  transpose_f32_bf16<<<dim3(H_DIM / 32, NCOL2 / 32), 256, 0, stream>>>(w_out, w2t, NCOL2, H_DIM);
  attn_fused<<<NH * (T_DIM / 16), 256, 0, stream>>>(qb, kf, vf, bias, comb);
  gemm256<2><<<(T_DIM / 256) * (H_DIM / 256) * KSPLIT, 512, 0, stream>>>(
      comb, w2t, b_out, part, T_DIM, H_DIM, NCOL2, KSLEN);
  reduce_split<<<(T_DIM * H_DIM / 4) / 256, 256, 0, stream>>>(part, b_out, (float*)d_out);
}

// Round 13
// 565.974 us; speedup vs baseline: 1.2055x; 1.2055x over previous
//
#include <hip/hip_runtime.h>
#include <stdint.h>

typedef unsigned short u16;
typedef __attribute__((ext_vector_type(8))) short short8;
typedef __attribute__((ext_vector_type(4))) short short4v;
typedef __attribute__((ext_vector_type(4))) float floatx4;

#define T_DIM 2048
#define NH    16
#define HD    128
#define H_DIM 2048
#define I_DIM 8192
#define NCOL1 22528   // 3H + 2I
#define NCOL2 10240   // H + I
#define PADW  1036    // LDS words per bias row (1024 + pad; %4==0, 2-way banks)
#define KSPLIT 4
#define KSLEN  (NCOL2 / KSPLIT)   // 2560

#define VMBAR(n) asm volatile("s_waitcnt vmcnt(" #n ")\n\ts_barrier" ::: "memory")

__device__ __forceinline__ float bf2f(u16 b) {
  union { uint32_t u; float f; } x; x.u = ((uint32_t)b) << 16; return x.f;
}
__device__ __forceinline__ u16 f2bf(float f) {
  union { float f; uint32_t u; } x; x.f = f;
  uint32_t r = x.u + 0x7fffu + ((x.u >> 16) & 1u);
  return (u16)(r >> 16);
}

__device__ __forceinline__ void gl_lds16(const void* g, void* l) {
  __builtin_amdgcn_global_load_lds((const __attribute__((address_space(1))) void*)g,
                                   (__attribute__((address_space(3))) void*)l, 16, 0, 0);
}

__device__ __forceinline__ floatx4 mfma32(short8 a, short8 b, floatx4 c) {
  return __builtin_amdgcn_mfma_f32_16x16x32_bf16(a, b, c, 0, 0, 0);
}
__device__ __forceinline__ floatx4 mfma16(short4v a, short4v b, floatx4 c) {
#if __has_builtin(__builtin_amdgcn_mfma_f32_16x16x16bf16_1k)
  return __builtin_amdgcn_mfma_f32_16x16x16bf16_1k(a, b, c, 0, 0, 0);
#else
  asm volatile("v_mfma_f32_16x16x16_bf16 %0, %1, %2, %0" : "+v"(c) : "v"(a), "v"(b));
  return c;
#endif
}

// ---------------- RMSNorm + age override -> bf16 ----------------
__global__ __launch_bounds__(256) void rmsnorm_k(
    const float* __restrict__ x, const float* __restrict__ ages,
    const float* __restrict__ w, u16* __restrict__ xn) {
  int t = blockIdx.x, tid = threadIdx.x;
  const float* xr = x + (size_t)t * H_DIM;
  floatx4 a = *(const floatx4*)(xr + tid * 8);
  floatx4 b = *(const floatx4*)(xr + tid * 8 + 4);
  float ss = a[0]*a[0]+a[1]*a[1]+a[2]*a[2]+a[3]*a[3]
           + b[0]*b[0]+b[1]*b[1]+b[2]*b[2]+b[3]*b[3];
#pragma unroll
  for (int off = 32; off >= 1; off >>= 1) ss += __shfl_xor(ss, off);
  __shared__ float red[4];
  if ((tid & 63) == 0) red[tid >> 6] = ss;
  __syncthreads();
  float tot = red[0] + red[1] + red[2] + red[3];
  float rms = rsqrtf(tot * (1.0f / H_DIM) + 1e-6f);
  const float* wr = w + tid * 8;
  float v[8] = {a[0],a[1],a[2],a[3],b[0],b[1],b[2],b[3]};
  short8 o;
#pragma unroll
  for (int i = 0; i < 8; ++i) o[i] = (short)f2bf(v[i] * rms * wr[i]);
  if (tid == 255) {           // covers cols 2040..2047
    float ag = ages[t];
    o[6] = (short)f2bf(ag);
    o[7] = (short)f2bf(ag * ag);
  }
  *(short8*)(xn + (size_t)t * H_DIM + tid * 8) = o;
}

// ------------- fp32 (K,N) -> bf16 (N,K) transpose ---------------
__global__ __launch_bounds__(256) void transpose_f32_bf16(
    const float* __restrict__ in, u16* __restrict__ out, int K, int N) {
  __shared__ float tile[32][33];
  int n0 = blockIdx.x * 32, k0 = blockIdx.y * 32;
  int c = threadIdx.x & 31, r = threadIdx.x >> 5;
#pragma unroll
  for (int i = 0; i < 4; ++i) {
    int kk = r + i * 8;
    tile[c][kk] = in[(size_t)(k0 + kk) * N + n0 + c];
  }
  __syncthreads();
#pragma unroll
  for (int i = 0; i < 4; ++i) {
    int nn = r + i * 8;
    out[(size_t)(n0 + nn) * K + k0 + c] = f2bf(tile[nn][c]);
  }
}

// ---- bf16 GEMM, B^T (N-major), 256x256 tile, 8 waves, ring-2 (R13) -------
// 64KB LDS (2 x 32KB slots) -> 2 blocks/CU: the co-resident block hides the
// per-tile vmcnt(0) drain (m114 implicit overlap). Stage(t+1) issues at the
// TOP of iter t (slot (t+1)&1, retired by the barrier ending iter t-1), so
// the drain at the boundary waits loads issued ~600+ cycles earlier.
// Swizzle: phys k16 = lg ^ ((lq>>1)&3); staging pre-swizzles global source.
// OUTF: 0 bf16+bias, 1 f32+bias, 2 f32 split-K partial (at Cout + sp*M*N).
template<int OUTF>
__global__ __launch_bounds__(512, 2) void gemm256(
    const u16* __restrict__ A, const u16* __restrict__ B,
    const float* __restrict__ bias, void* __restrict__ Cout,
    int M, int N, int K, int klen) {
  __shared__ __align__(16) u16 sm[32768];   // 2 slots x (A 8192 + B 8192) u16
  int nbm = M >> 8, nbn = N >> 8;
  int per = nbm * nbn;
  int nwg = per * (K / klen);
  int bid = blockIdx.x;
  int swz = (bid & 7) * (nwg >> 3) + (bid >> 3);   // XCD swizzle (nwg%8==0)
  int sp = swz / per, rr = swz % per;
  int bn = rr / nbm, bm = rr % nbm;                // bn-major (B-panel reuse)
  int kbeg = sp * klen;
  int tid = threadIdx.x, lane = tid & 63;
  int wid = tid >> 6;            // 0..7
  int wrow = wid >> 2;           // 0..1 (M half)
  int wcol = wid & 3;            // 0..3 (N quarter)
  int lq = lane & 15, lg = lane >> 4;

  // staging: thread tid covers rows (tid>>2) and 128+(tid>>2); 16B each.
  int srow = tid >> 2;
  int scol = ((tid & 3) ^ ((tid >> 3) & 3)) << 3;   // pre-swizzled src col (u16)
  const u16* Ag0 = A + (size_t)(bm * 256 + srow) * K + kbeg + scol;
  const u16* Ag1 = Ag0 + (size_t)128 * K;
  const u16* Bg0 = B + (size_t)(bn * 256 + srow) * K + kbeg + scol;
  const u16* Bg1 = Bg0 + (size_t)128 * K;
  u16* Ad0 = sm + tid * 8;           // linear LDS dest; addr(row,k16)=row*32+k16*8
  u16* Ad1 = sm + 4096 + tid * 8;
  u16* Bd0 = sm + 8192 + tid * 8;
  u16* Bd1 = sm + 12288 + tid * 8;

  // frag read offsets (physical = logical k16 XOR ((lq>>1)&3))
  int xorc = ((lq >> 1) & 3) << 3;
  int aoff = (wrow * 128 + lq) * 32 + ((lg * 8) ^ xorc);
  int boff = 8192 + (wcol * 64 + lq) * 32 + ((lg * 8) ^ xorc);

  floatx4 acc[8][4] = {};
  const int NT = klen >> 5;

  auto STAGE = [&](int t) {
    int sl = (t & 1) * 16384;
    int ko = t * 32;
    gl_lds16(Ag0 + ko, Ad0 + sl);
    gl_lds16(Ag1 + ko, Ad1 + sl);
    gl_lds16(Bg0 + ko, Bd0 + sl);
    gl_lds16(Bg1 + ko, Bd1 + sl);
  };

  STAGE(0); STAGE(1);
  VMBAR(4);   // tile 0 resident; tile 1's 4 loads may stay in flight

  for (int t = 0; t < NT; ++t) {
    if (t >= 1 && t + 1 < NT) STAGE(t + 1);   // slot (t+1)&1, retired last iter
    const u16* sb = sm + (t & 1) * 16384;
    short8 af[8], bfr[4];
#pragma unroll
    for (int i = 0; i < 8; ++i) af[i]  = *(const short8*)(sb + aoff + i * 512);
#pragma unroll
    for (int i = 0; i < 4; ++i) bfr[i] = *(const short8*)(sb + boff + i * 512);
    __builtin_amdgcn_s_setprio(1);
#pragma unroll
    for (int mi = 0; mi < 8; ++mi)
#pragma unroll
      for (int ni = 0; ni < 4; ++ni)
        acc[mi][ni] = mfma32(af[mi], bfr[ni], acc[mi][ni]);
    __builtin_amdgcn_s_setprio(0);
    VMBAR(0);   // tile t+1 resident; drain covered by co-resident block
  }

#pragma unroll
  for (int mi = 0; mi < 8; ++mi) {
#pragma unroll
    for (int ni = 0; ni < 4; ++ni) {
      int col = bn * 256 + wcol * 64 + ni * 16 + lq;
      float bv = (OUTF == 2) ? 0.f : bias[col];
#pragma unroll
      for (int j = 0; j < 4; ++j) {
        int row = bm * 256 + wrow * 128 + mi * 16 + lg * 4 + j;
        float vv = acc[mi][ni][j] + bv;
        if (OUTF == 0)      ((u16*)Cout)[(size_t)row * N + col] = f2bf(vv);
        else if (OUTF == 1) ((float*)Cout)[(size_t)row * N + col] = vv;
        else ((float*)Cout)[(size_t)sp * M * N + (size_t)row * N + col] = vv;
      }
    }
  }
}

// ---- reduce split-K partials + bias -> f32 out ------------------
__global__ __launch_bounds__(256) void reduce_split(
    const float* __restrict__ part, const float* __restrict__ bias,
    float* __restrict__ out) {
  size_t idx = ((size_t)blockIdx.x * 256 + threadIdx.x) * 4;
  int col = (int)(idx & (H_DIM - 1));
  floatx4 acc = *(const floatx4*)(bias + col);
#pragma unroll
  for (int s = 0; s < KSPLIT; ++s) {
    floatx4 p = *(const floatx4*)(part + (size_t)s * T_DIM * H_DIM + idx);
#pragma unroll
    for (int j = 0; j < 4; ++j) acc[j] += p[j];
  }
  *(floatx4*)(out + idx) = acc;
}

// ---- RoPE on q,k; split qkv; K,V stored in MFMA-fragment order ----
__global__ __launch_bounds__(256) void rope_split(
    const u16* __restrict__ tb, const float* __restrict__ sinp, const float* __restrict__ cosp,
    u16* __restrict__ qb, u16* __restrict__ kf, u16* __restrict__ vf) {
  __shared__ u16 vtile[32][130];
  int t0 = blockIdx.x * 32, h = blockIdx.y, tid = threadIdx.x;
  int r = tid >> 3, d0 = (tid & 7) << 4;
  int t = t0 + r;
  const u16* base = tb + (size_t)t * NCOL1 + 2 * I_DIM + h * HD + d0;
  const float* cp = cosp + (size_t)t * HD + d0;
  const float* sp = sinp + (size_t)t * HD + d0;
  float cv[16], sv[16];
#pragma unroll
  for (int i = 0; i < 16; i += 4) {
    *(floatx4*)(cv + i) = *(const floatx4*)(cp + i);
    *(floatx4*)(sv + i) = *(const floatx4*)(sp + i);
  }
#pragma unroll
  for (int s = 0; s < 2; ++s) {
    const u16* src = base + s * (NH * HD);
    short8 x0 = *(const short8*)src;
    short8 x1 = *(const short8*)(src + 8);
    float xf[16];
#pragma unroll
    for (int i = 0; i < 8; ++i) { xf[i] = bf2f((u16)x0[i]); xf[8 + i] = bf2f((u16)x1[i]); }
    short8 o0, o1;
#pragma unroll
    for (int i = 0; i < 8; i += 2) {
      o0[i]     = (short)f2bf(xf[i] * cv[i] - xf[i + 1] * sv[i]);
      o0[i + 1] = (short)f2bf(xf[i + 1] * cv[i + 1] + xf[i] * sv[i + 1]);
      o1[i]     = (short)f2bf(xf[8 + i] * cv[8 + i] - xf[9 + i] * sv[8 + i]);
      o1[i + 1] = (short)f2bf(xf[9 + i] * cv[9 + i] + xf[8 + i] * sv[9 + i]);
    }
    if (s == 0) {
      u16* dst = qb + ((size_t)h * T_DIM + t) * HD + d0;
      *(short8*)dst = o0;
      *(short8*)(dst + 8) = o1;
    } else {
      int s16 = t >> 4, tt = d0 >> 5, lg0 = (d0 >> 3) & 3;
      size_t cb = (((size_t)h * 128 + s16) * 4 + tt) * 512 + ((t & 15) + 16 * lg0) * 8;
      *(short8*)(kf + cb) = o0;          // lg0
      *(short8*)(kf + cb + 128) = o1;    // lg0+1
    }
  }
  short8 v0 = *(const short8*)(base + 2 * NH * HD);
  short8 v1 = *(const short8*)(base + 2 * NH * HD + 8);
#pragma unroll
  for (int i = 0; i < 8; ++i) {
    vtile[r][d0 + i]     = (u16)v0[i];
    vtile[r][d0 + 8 + i] = (u16)v1[i];
  }
  __syncthreads();
  {
    int d = tid >> 1, th = (tid & 1) << 4;
    int s16 = (t0 + th) >> 4;
    int dp = d >> 5, par = (d >> 4) & 1, lqv = d & 15;
    size_t cb = (((size_t)h * 128 + s16) * 4 + dp) * 512 + par * 4;
#pragma unroll
    for (int lg = 0; lg < 4; ++lg) {
      short4v g;
#pragma unroll
      for (int j = 0; j < 4; ++j) g[j] = (short)vtile[th + lg * 4 + j][d];
      *(short4v*)(vf + cb + (size_t)(lqv + 16 * lg) * 8) = g;
    }
  }
}

// -------------------- silu(x1)*x2 -> comb[:, H:] -----------------
__global__ __launch_bounds__(256) void silu_mul(
    const u16* __restrict__ tb, u16* __restrict__ comb) {
  int idx = blockIdx.x * 256 + threadIdx.x;
  int t = idx >> 10;
  int j = (idx & 1023) << 3;
  const u16* p1 = tb + (size_t)t * NCOL1 + j;
  const u16* p2 = p1 + I_DIM;
  short8 a = *(const short8*)p1;
  short8 b = *(const short8*)p2;
  short8 o;
#pragma unroll
  for (int i = 0; i < 8; ++i) {
    float x1 = bf2f((u16)a[i]), x2 = bf2f((u16)b[i]);
    float s = x1 / (1.0f + __expf(-x1));
    o[i] = (short)f2bf(s * x2);
  }
  *(short8*)(comb + (size_t)t * NCOL2 + H_DIM + j) = o;
}

// ---- fused flash attention; bias dense in LDS; K/V fragment-packed ----
// R8 version (best measured): tile=1024 (4KB bias rows), 66KB LDS, 2 blk/CU,
// unconditional online-softmax rescale.
__global__ __launch_bounds__(256) void attn_fused(
    const u16* __restrict__ Q, const u16* __restrict__ kf,
    const u16* __restrict__ vf, const float* __restrict__ bias,
    u16* __restrict__ comb) {
  __shared__ float lds[16 * PADW];   // 66,304 B; reused for the final merge
  int bid = blockIdx.x;
  int swz = (bid & 7) * 256 + (bid >> 3);   // 2048 blocks, bijective XCD swizzle
  int h = swz >> 7, qt = swz & 127;
  int q0 = qt * 16;
  int tid = threadIdx.x;
  int w = tid >> 6, lane = tid & 63;
  int lq = lane & 15, lg = lane >> 4;

  const u16* Qp = Q + ((size_t)h * T_DIM + q0 + lq) * HD + lg * 8;
  const u16* Kf = kf + ((size_t)h * 128) * 2048 + lane * 8;  // + s16*2048 + t*512
  const u16* Vf = vf + ((size_t)h * 128) * 2048 + lane * 8;  // + s16*2048 + dp*512
  const float* Bh = bias + ((size_t)h * T_DIM + q0) * T_DIM;

  short8 qf[4];
#pragma unroll
  for (int t = 0; t < 4; ++t) qf[t] = *(const short8*)(Qp + t * 32);

  floatx4 o[8] = {};
  float m = -1e30f, l = 0.f;
  const float sc = 0.08838834764831845f;   // 1/sqrt(128)

#pragma unroll
  for (int tile = 0; tile < 2; ++tile) {
    // ---- stage bias tile: 16 rows x 4KB contiguous each ----
#pragma unroll
    for (int r = 0; r < 16; ++r) {
      const float* src = Bh + (size_t)r * T_DIM + tile * 1024 + tid * 4;
      gl_lds16(src, &lds[r * PADW + tid * 4]);
    }
    __syncthreads();   // drains vmcnt -> tile resident
    // ---- each wave: 8 sub-bodies of 32 s, strided by 128 ----
#pragma unroll
    for (int sub = 0; sub < 8; ++sub) {
      int soff = sub * 128 + w * 32;          // offset within tile
      int s0 = tile * 1024 + soff;            // global s
      int s16a = s0 >> 4;
      const u16* ka = Kf + (size_t)s16a * 2048;
      floatx4 st0 = {0.f,0.f,0.f,0.f}, st1 = {0.f,0.f,0.f,0.f};
#pragma unroll
      for (int t = 0; t < 4; ++t) {
        st0 = mfma32(*(const short8*)(ka + t * 512), qf[t], st0);
        st1 = mfma32(*(const short8*)(ka + 2048 + t * 512), qf[t], st1);
      }
      floatx4 b0 = *(const floatx4*)&lds[lq * PADW + soff + lg * 4];
      floatx4 b1 = *(const floatx4*)&lds[lq * PADW + soff + lg * 4 + 16];
      float p[8]; float tmax = -1e30f;
#pragma unroll
      for (int j = 0; j < 4; ++j) {
        p[j]     = st0[j] * sc + b0[j];
        p[4 + j] = st1[j] * sc + b1[j];
        tmax = fmaxf(tmax, fmaxf(p[j], p[4 + j]));
      }
      tmax = fmaxf(tmax, __shfl_xor(tmax, 16));
      tmax = fmaxf(tmax, __shfl_xor(tmax, 32));
      float mn = fmaxf(m, tmax);
      float alpha = __expf(m - mn);
      float rs = 0.f;
      short4v pb0, pb1;
#pragma unroll
      for (int j = 0; j < 4; ++j) {
        float e0 = __expf(p[j] - mn), e1 = __expf(p[4 + j] - mn);
        rs += e0 + e1;
        pb0[j] = (short)f2bf(e0);
        pb1[j] = (short)f2bf(e1);
      }
      rs += __shfl_xor(rs, 16);
      rs += __shfl_xor(rs, 32);
      l = l * alpha + rs; m = mn;
#pragma unroll
      for (int dt = 0; dt < 8; ++dt) o[dt] *= alpha;
      const u16* vb = Vf + (size_t)s16a * 2048;
#pragma unroll
      for (int dp = 0; dp < 4; ++dp) {
        short8 wa = *(const short8*)(vb + dp * 512);
        short8 wb = *(const short8*)(vb + 2048 + dp * 512);
        short4v a0 = {wa[0], wa[1], wa[2], wa[3]};
        short4v a1 = {wa[4], wa[5], wa[6], wa[7]};
        short4v c0 = {wb[0], wb[1], wb[2], wb[3]};
        short4v c1 = {wb[4], wb[5], wb[6], wb[7]};
        o[2*dp]     = mfma16(a0, pb0, o[2*dp]);
        o[2*dp + 1] = mfma16(a1, pb0, o[2*dp + 1]);
        o[2*dp]     = mfma16(c0, pb1, o[2*dp]);
        o[2*dp + 1] = mfma16(c1, pb1, o[2*dp + 1]);
      }
    }
    __syncthreads();   // all waves done reading before restage/merge
  }

  // ---- in-block 4-way (m,l,o) merge via LDS ----
  if (lg == 0) { lds[8448 + w * 16 + lq] = m; lds[8512 + w * 16 + lq] = l; }
  __syncthreads();
  float M = -1e30f;
#pragma unroll
  for (int i = 0; i < 4; ++i) M = fmaxf(M, lds[8448 + i * 16 + lq]);
  float scale = __expf(m - M);
#pragma unroll
  for (int dt = 0; dt < 8; ++dt) {
    floatx4 so = o[dt] * scale;
    *(floatx4*)&lds[w * 2112 + lq * 132 + dt * 16 + lg * 4] = so;
  }
  __syncthreads();
  // final reduce + normalize + write: thread t -> row t>>4, d0 = (t&15)*8
  {
    int row = tid >> 4, d0 = (tid & 15) * 8;
    float M2 = -1e30f;
#pragma unroll
    for (int i = 0; i < 4; ++i) M2 = fmaxf(M2, lds[8448 + i * 16 + row]);
    float den = 0.f;
#pragma unroll
    for (int i = 0; i < 4; ++i)
      den += __expf(lds[8448 + i * 16 + row] - M2) * lds[8512 + i * 16 + row];
    float inv = 1.0f / den;
    short8 ov;
#pragma unroll
    for (int k = 0; k < 8; ++k) {
      float s = 0.f;
#pragma unroll
      for (int i = 0; i < 4; ++i) s += lds[i * 2112 + row * 132 + d0 + k];
      ov[k] = (short)f2bf(s * inv);
    }
    *(short8*)(comb + (size_t)(q0 + row) * NCOL2 + h * HD + d0) = ov;
  }
}

extern "C" void kernel_launch(void* const* d_in, const int* in_sizes, int n_in,
                              void* d_out, int out_size, void* d_ws, size_t ws_size,
                              hipStream_t stream) {
  (void)in_sizes; (void)n_in; (void)out_size; (void)ws_size;
  const float* x     = (const float*)d_in[0];
  const float* ages  = (const float*)d_in[1];
  const float* sinp  = (const float*)d_in[2];
  const float* cosp  = (const float*)d_in[3];
  const float* bias  = (const float*)d_in[4];
  const float* normw = (const float*)d_in[5];
  const float* w_in  = (const float*)d_in[6];
  const float* b_in  = (const float*)d_in[7];
  const float* w_out = (const float*)d_in[8];
  const float* b_out = (const float*)d_in[9];

  char* ws = (char*)d_ws;
  const size_t SZ_XN   = (size_t)T_DIM * H_DIM * 2;      //  8 MiB
  const size_t SZ_W1T  = (size_t)NCOL1 * H_DIM * 2;      //  88 MiB
  const size_t SZ_T    = (size_t)T_DIM * NCOL1 * 2;      //  88 MiB
  const size_t SZ_HEAD = (size_t)NH * T_DIM * HD * 2;    //   8 MiB
  u16* xn   = (u16*)(ws);
  u16* w1t  = (u16*)(ws + SZ_XN);
  u16* tb   = (u16*)(ws + SZ_XN + SZ_W1T);
  u16* qb   = (u16*)(ws + SZ_XN + SZ_W1T + SZ_T);
  u16* kf   = (u16*)(ws + SZ_XN + SZ_W1T + SZ_T + SZ_HEAD);
  u16* vf   = (u16*)(ws + SZ_XN + SZ_W1T + SZ_T + 2 * SZ_HEAD);
  u16* w2t  = (u16*)(ws + SZ_XN);                  // reuse w1t region (dead after GEMM1)
  u16* comb = (u16*)(ws + SZ_XN + (48ull << 20));  // also inside w1t region, disjoint from w2t
  float* part = (float*)tb;                        // split-K partials (64 MiB) in dead tb region

  rmsnorm_k<<<T_DIM, 256, 0, stream>>>(x, ages, normw, xn);
  transpose_f32_bf16<<<dim3(NCOL1 / 32, H_DIM / 32), 256, 0, stream>>>(w_in, w1t, H_DIM, NCOL1);
  gemm256<0><<<(T_DIM / 256) * (NCOL1 / 256), 512, 0, stream>>>(
      xn, w1t, b_in, tb, T_DIM, NCOL1, H_DIM, H_DIM);
  rope_split<<<dim3(T_DIM / 32, NH), 256, 0, stream>>>(tb, sinp, cosp, qb, kf, vf);
  silu_mul<<<(T_DIM * I_DIM) / (256 * 8), 256, 0, stream>>>(tb, comb);
  transpose_f32_bf16<<<dim3(H_DIM / 32, NCOL2 / 32), 256, 0, stream>>>(w_out, w2t, NCOL2, H_DIM);
  attn_fused<<<NH * (T_DIM / 16), 256, 0, stream>>>(qb, kf, vf, bias, comb);
  gemm256<2><<<(T_DIM / 256) * (H_DIM / 256) * KSPLIT, 512, 0, stream>>>(
      comb, w2t, b_out, part, T_DIM, H_DIM, NCOL2, KSLEN);
  reduce_split<<<(T_DIM * H_DIM / 4) / 256, 256, 0, stream>>>(part, b_out, (float*)d_out);
}

// Round 14
// 543.082 us; speedup vs baseline: 1.2563x; 1.0422x over previous
//
#include <hip/hip_runtime.h>
#include <stdint.h>

typedef unsigned short u16;
typedef __attribute__((ext_vector_type(8))) short short8;
typedef __attribute__((ext_vector_type(4))) short short4v;
typedef __attribute__((ext_vector_type(4))) float floatx4;

#define T_DIM 2048
#define NH    16
#define HD    128
#define H_DIM 2048
#define I_DIM 8192
#define NCOL1 22528   // 3H + 2I
#define NCOL2 10240   // H + I
#define PADW  1036    // LDS words per bias row (1024 + pad; %4==0, 2-way banks)
#define KSPLIT 4
#define KSLEN  (NCOL2 / KSPLIT)   // 2560

#define VMBAR(n) asm volatile("s_waitcnt vmcnt(" #n ")\n\ts_barrier" ::: "memory")

__device__ __forceinline__ float bf2f(u16 b) {
  union { uint32_t u; float f; } x; x.u = ((uint32_t)b) << 16; return x.f;
}
__device__ __forceinline__ u16 f2bf(float f) {
  union { float f; uint32_t u; } x; x.f = f;
  uint32_t r = x.u + 0x7fffu + ((x.u >> 16) & 1u);
  return (u16)(r >> 16);
}

__device__ __forceinline__ void gl_lds16(const void* g, void* l) {
  __builtin_amdgcn_global_load_lds((const __attribute__((address_space(1))) void*)g,
                                   (__attribute__((address_space(3))) void*)l, 16, 0, 0);
}

__device__ __forceinline__ floatx4 mfma32(short8 a, short8 b, floatx4 c) {
  return __builtin_amdgcn_mfma_f32_16x16x32_bf16(a, b, c, 0, 0, 0);
}
__device__ __forceinline__ floatx4 mfma16(short4v a, short4v b, floatx4 c) {
#if __has_builtin(__builtin_amdgcn_mfma_f32_16x16x16bf16_1k)
  return __builtin_amdgcn_mfma_f32_16x16x16bf16_1k(a, b, c, 0, 0, 0);
#else
  asm volatile("v_mfma_f32_16x16x16_bf16 %0, %1, %2, %0" : "+v"(c) : "v"(a), "v"(b));
  return c;
#endif
}

// ---------------- RMSNorm + age override -> bf16 ----------------
__global__ __launch_bounds__(256) void rmsnorm_k(
    const float* __restrict__ x, const float* __restrict__ ages,
    const float* __restrict__ w, u16* __restrict__ xn) {
  int t = blockIdx.x, tid = threadIdx.x;
  const float* xr = x + (size_t)t * H_DIM;
  floatx4 a = *(const floatx4*)(xr + tid * 8);
  floatx4 b = *(const floatx4*)(xr + tid * 8 + 4);
  float ss = a[0]*a[0]+a[1]*a[1]+a[2]*a[2]+a[3]*a[3]
           + b[0]*b[0]+b[1]*b[1]+b[2]*b[2]+b[3]*b[3];
#pragma unroll
  for (int off = 32; off >= 1; off >>= 1) ss += __shfl_xor(ss, off);
  __shared__ float red[4];
  if ((tid & 63) == 0) red[tid >> 6] = ss;
  __syncthreads();
  float tot = red[0] + red[1] + red[2] + red[3];
  float rms = rsqrtf(tot * (1.0f / H_DIM) + 1e-6f);
  const float* wr = w + tid * 8;
  float v[8] = {a[0],a[1],a[2],a[3],b[0],b[1],b[2],b[3]};
  short8 o;
#pragma unroll
  for (int i = 0; i < 8; ++i) o[i] = (short)f2bf(v[i] * rms * wr[i]);
  if (tid == 255) {           // covers cols 2040..2047
    float ag = ages[t];
    o[6] = (short)f2bf(ag);
    o[7] = (short)f2bf(ag * ag);
  }
  *(short8*)(xn + (size_t)t * H_DIM + tid * 8) = o;
}

// ------------- fp32 (K,N) -> bf16 (N,K) transpose ---------------
__global__ __launch_bounds__(256) void transpose_f32_bf16(
    const float* __restrict__ in, u16* __restrict__ out, int K, int N) {
  __shared__ float tile[32][33];
  int n0 = blockIdx.x * 32, k0 = blockIdx.y * 32;
  int c = threadIdx.x & 31, r = threadIdx.x >> 5;
#pragma unroll
  for (int i = 0; i < 4; ++i) {
    int kk = r + i * 8;
    tile[c][kk] = in[(size_t)(k0 + kk) * N + n0 + c];
  }
  __syncthreads();
#pragma unroll
  for (int i = 0; i < 4; ++i) {
    int nn = r + i * 8;
    out[(size_t)(n0 + nn) * K + k0 + c] = f2bf(tile[nn][c]);
  }
}

// ---- bf16 GEMM, B^T (N-major), 256x256 tile, 8 waves, ring-4 + reg-prefetch
// R14: R8's ring-4 counted-vmcnt pipeline, plus cross-tile register prefetch
// of next tile's a[0..3]+b[0..3] fragments (8 ds_reads with no same-iter
// consumer -> overlap the MFMA cluster); only a[4..7] is read at the top of
// the iter (consumed by the LAST 16 MFMAs -> latency hidden by first 16).
// Boundary = vmcnt(4)+barrier: tile t+2 resident for next iter's prefetch.
// MFMA order identical to R8 -> bit-identical numerics.
// OUTF: 0 bf16+bias, 1 f32+bias, 2 f32 split-K partial (at Cout + sp*M*N).
template<int OUTF>
__global__ __launch_bounds__(512, 2) void gemm256(
    const u16* __restrict__ A, const u16* __restrict__ B,
    const float* __restrict__ bias, void* __restrict__ Cout,
    int M, int N, int K, int klen) {
  __shared__ __align__(16) u16 sm[65536];   // 4 slots x (A 8192 + B 8192) u16
  int nbm = M >> 8, nbn = N >> 8;
  int per = nbm * nbn;
  int nwg = per * (K / klen);
  int bid = blockIdx.x;
  int swz = (bid & 7) * (nwg >> 3) + (bid >> 3);   // XCD swizzle (nwg%8==0)
  int sp = swz / per, rr = swz % per;
  int bn = rr / nbm, bm = rr % nbm;                // bn-major (B-panel reuse)
  int kbeg = sp * klen;
  int tid = threadIdx.x, lane = tid & 63;
  int wid = tid >> 6;            // 0..7
  int wrow = wid >> 2;           // 0..1 (M half)
  int wcol = wid & 3;            // 0..3 (N quarter)
  int lq = lane & 15, lg = lane >> 4;

  // staging: thread tid covers rows (tid>>2) and 128+(tid>>2); 16B each.
  int srow = tid >> 2;
  int scol = ((tid & 3) ^ ((tid >> 3) & 3)) << 3;   // pre-swizzled src col (u16)
  const u16* Ag0 = A + (size_t)(bm * 256 + srow) * K + kbeg + scol;
  const u16* Ag1 = Ag0 + (size_t)128 * K;
  const u16* Bg0 = B + (size_t)(bn * 256 + srow) * K + kbeg + scol;
  const u16* Bg1 = Bg0 + (size_t)128 * K;
  u16* Ad0 = sm + tid * 8;           // linear LDS dest; addr(row,k16)=row*32+k16*8
  u16* Ad1 = sm + 4096 + tid * 8;
  u16* Bd0 = sm + 8192 + tid * 8;
  u16* Bd1 = sm + 12288 + tid * 8;

  // frag read offsets (physical = logical k16 XOR ((lq>>1)&3))
  int xorc = ((lq >> 1) & 3) << 3;
  int aoff = (wrow * 128 + lq) * 32 + ((lg * 8) ^ xorc);
  int boff = 8192 + (wcol * 64 + lq) * 32 + ((lg * 8) ^ xorc);

  floatx4 acc[8][4] = {};
  const int NT = klen >> 5;   // even for both call sites (64, 80)

  auto STAGE = [&](int t) {
    int sl = (t & 3) * 16384;
    int ko = t * 32;
    gl_lds16(Ag0 + ko, Ad0 + sl);
    gl_lds16(Ag1 + ko, Ad1 + sl);
    gl_lds16(Bg0 + ko, Bd0 + sl);
    gl_lds16(Bg1 + ko, Bd1 + sl);
  };

  short8 a47[4];
  short8 aX[4], bX[4], aY[4], bY[4];

  auto RD_A47 = [&](int slot) {
    const u16* sb = sm + slot * 16384;
#pragma unroll
    for (int i = 0; i < 4; ++i) a47[i] = *(const short8*)(sb + aoff + (4 + i) * 512);
  };
  auto RD_PF = [&](int slot, short8* a, short8* b) {
    const u16* sb = sm + slot * 16384;
#pragma unroll
    for (int i = 0; i < 4; ++i) a[i] = *(const short8*)(sb + aoff + i * 512);
#pragma unroll
    for (int i = 0; i < 4; ++i) b[i] = *(const short8*)(sb + boff + i * 512);
  };
  auto COMPUTE = [&](short8* a03, short8* b) {
    __builtin_amdgcn_s_setprio(1);
#pragma unroll
    for (int mi = 0; mi < 4; ++mi)
#pragma unroll
      for (int ni = 0; ni < 4; ++ni)
        acc[mi][ni] = mfma32(a03[mi], b[ni], acc[mi][ni]);
#pragma unroll
    for (int mi = 4; mi < 8; ++mi)
#pragma unroll
      for (int ni = 0; ni < 4; ++ni)
        acc[mi][ni] = mfma32(a47[mi - 4], b[ni], acc[mi][ni]);
    __builtin_amdgcn_s_setprio(0);
  };

  STAGE(0); STAGE(1); STAGE(2);
  VMBAR(4);            // tiles 0,1 resident; tile 2's 4 loads in flight
  RD_PF(0, aX, bX);    // tile 0 a03/b into X

  for (int t = 0; t < NT; t += 2) {
    // ---- iter t: compute from X, prefetch t+1 into Y ----
    RD_A47(t & 3);
    RD_PF((t + 1) & 3, aY, bY);
    if (t + 3 < NT) STAGE(t + 3);
    COMPUTE(aX, bX);
    if (t + 3 < NT) VMBAR(4); else VMBAR(0);
    // ---- iter t+1: compute from Y, prefetch t+2 into X ----
    RD_A47((t + 1) & 3);
    if (t + 2 < NT) RD_PF((t + 2) & 3, aX, bX);
    if (t + 4 < NT) STAGE(t + 4);
    COMPUTE(aY, bY);
    if (t + 4 < NT) VMBAR(4); else VMBAR(0);
  }

#pragma unroll
  for (int mi = 0; mi < 8; ++mi) {
#pragma unroll
    for (int ni = 0; ni < 4; ++ni) {
      int col = bn * 256 + wcol * 64 + ni * 16 + lq;
      float bv = (OUTF == 2) ? 0.f : bias[col];
#pragma unroll
      for (int j = 0; j < 4; ++j) {
        int row = bm * 256 + wrow * 128 + mi * 16 + lg * 4 + j;
        float vv = acc[mi][ni][j] + bv;
        if (OUTF == 0)      ((u16*)Cout)[(size_t)row * N + col] = f2bf(vv);
        else if (OUTF == 1) ((float*)Cout)[(size_t)row * N + col] = vv;
        else ((float*)Cout)[(size_t)sp * M * N + (size_t)row * N + col] = vv;
      }
    }
  }
}

// ---- reduce split-K partials + bias -> f32 out ------------------
__global__ __launch_bounds__(256) void reduce_split(
    const float* __restrict__ part, const float* __restrict__ bias,
    float* __restrict__ out) {
  size_t idx = ((size_t)blockIdx.x * 256 + threadIdx.x) * 4;
  int col = (int)(idx & (H_DIM - 1));
  floatx4 acc = *(const floatx4*)(bias + col);
#pragma unroll
  for (int s = 0; s < KSPLIT; ++s) {
    floatx4 p = *(const floatx4*)(part + (size_t)s * T_DIM * H_DIM + idx);
#pragma unroll
    for (int j = 0; j < 4; ++j) acc[j] += p[j];
  }
  *(floatx4*)(out + idx) = acc;
}

// ---- RoPE on q,k; split qkv; K,V stored in MFMA-fragment order ----
__global__ __launch_bounds__(256) void rope_split(
    const u16* __restrict__ tb, const float* __restrict__ sinp, const float* __restrict__ cosp,
    u16* __restrict__ qb, u16* __restrict__ kf, u16* __restrict__ vf) {
  __shared__ u16 vtile[32][130];
  int t0 = blockIdx.x * 32, h = blockIdx.y, tid = threadIdx.x;
  int r = tid >> 3, d0 = (tid & 7) << 4;
  int t = t0 + r;
  const u16* base = tb + (size_t)t * NCOL1 + 2 * I_DIM + h * HD + d0;
  const float* cp = cosp + (size_t)t * HD + d0;
  const float* sp = sinp + (size_t)t * HD + d0;
  float cv[16], sv[16];
#pragma unroll
  for (int i = 0; i < 16; i += 4) {
    *(floatx4*)(cv + i) = *(const floatx4*)(cp + i);
    *(floatx4*)(sv + i) = *(const floatx4*)(sp + i);
  }
#pragma unroll
  for (int s = 0; s < 2; ++s) {
    const u16* src = base + s * (NH * HD);
    short8 x0 = *(const short8*)src;
    short8 x1 = *(const short8*)(src + 8);
    float xf[16];
#pragma unroll
    for (int i = 0; i < 8; ++i) { xf[i] = bf2f((u16)x0[i]); xf[8 + i] = bf2f((u16)x1[i]); }
    short8 o0, o1;
#pragma unroll
    for (int i = 0; i < 8; i += 2) {
      o0[i]     = (short)f2bf(xf[i] * cv[i] - xf[i + 1] * sv[i]);
      o0[i + 1] = (short)f2bf(xf[i + 1] * cv[i + 1] + xf[i] * sv[i + 1]);
      o1[i]     = (short)f2bf(xf[8 + i] * cv[8 + i] - xf[9 + i] * sv[8 + i]);
      o1[i + 1] = (short)f2bf(xf[9 + i] * cv[9 + i] + xf[8 + i] * sv[9 + i]);
    }
    if (s == 0) {
      u16* dst = qb + ((size_t)h * T_DIM + t) * HD + d0;
      *(short8*)dst = o0;
      *(short8*)(dst + 8) = o1;
    } else {
      int s16 = t >> 4, tt = d0 >> 5, lg0 = (d0 >> 3) & 3;
      size_t cb = (((size_t)h * 128 + s16) * 4 + tt) * 512 + ((t & 15) + 16 * lg0) * 8;
      *(short8*)(kf + cb) = o0;          // lg0
      *(short8*)(kf + cb + 128) = o1;    // lg0+1
    }
  }
  short8 v0 = *(const short8*)(base + 2 * NH * HD);
  short8 v1 = *(const short8*)(base + 2 * NH * HD + 8);
#pragma unroll
  for (int i = 0; i < 8; ++i) {
    vtile[r][d0 + i]     = (u16)v0[i];
    vtile[r][d0 + 8 + i] = (u16)v1[i];
  }
  __syncthreads();
  {
    int d = tid >> 1, th = (tid & 1) << 4;
    int s16 = (t0 + th) >> 4;
    int dp = d >> 5, par = (d >> 4) & 1, lqv = d & 15;
    size_t cb = (((size_t)h * 128 + s16) * 4 + dp) * 512 + par * 4;
#pragma unroll
    for (int lg = 0; lg < 4; ++lg) {
      short4v g;
#pragma unroll
      for (int j = 0; j < 4; ++j) g[j] = (short)vtile[th + lg * 4 + j][d];
      *(short4v*)(vf + cb + (size_t)(lqv + 16 * lg) * 8) = g;
    }
  }
}

// -------------------- silu(x1)*x2 -> comb[:, H:] -----------------
__global__ __launch_bounds__(256) void silu_mul(
    const u16* __restrict__ tb, u16* __restrict__ comb) {
  int idx = blockIdx.x * 256 + threadIdx.x;
  int t = idx >> 10;
  int j = (idx & 1023) << 3;
  const u16* p1 = tb + (size_t)t * NCOL1 + j;
  const u16* p2 = p1 + I_DIM;
  short8 a = *(const short8*)p1;
  short8 b = *(const short8*)p2;
  short8 o;
#pragma unroll
  for (int i = 0; i < 8; ++i) {
    float x1 = bf2f((u16)a[i]), x2 = bf2f((u16)b[i]);
    float s = x1 / (1.0f + __expf(-x1));
    o[i] = (short)f2bf(s * x2);
  }
  *(short8*)(comb + (size_t)t * NCOL2 + H_DIM + j) = o;
}

// ---- fused flash attention; bias dense in LDS; K/V fragment-packed ----
// R8 version (best measured): tile=1024 (4KB bias rows), 66KB LDS, 2 blk/CU,
// unconditional online-softmax rescale.
__global__ __launch_bounds__(256) void attn_fused(
    const u16* __restrict__ Q, const u16* __restrict__ kf,
    const u16* __restrict__ vf, const float* __restrict__ bias,
    u16* __restrict__ comb) {
  __shared__ float lds[16 * PADW];   // 66,304 B; reused for the final merge
  int bid = blockIdx.x;
  int swz = (bid & 7) * 256 + (bid >> 3);   // 2048 blocks, bijective XCD swizzle
  int h = swz >> 7, qt = swz & 127;
  int q0 = qt * 16;
  int tid = threadIdx.x;
  int w = tid >> 6, lane = tid & 63;
  int lq = lane & 15, lg = lane >> 4;

  const u16* Qp = Q + ((size_t)h * T_DIM + q0 + lq) * HD + lg * 8;
  const u16* Kf = kf + ((size_t)h * 128) * 2048 + lane * 8;  // + s16*2048 + t*512
  const u16* Vf = vf + ((size_t)h * 128) * 2048 + lane * 8;  // + s16*2048 + dp*512
  const float* Bh = bias + ((size_t)h * T_DIM + q0) * T_DIM;

  short8 qf[4];
#pragma unroll
  for (int t = 0; t < 4; ++t) qf[t] = *(const short8*)(Qp + t * 32);

  floatx4 o[8] = {};
  float m = -1e30f, l = 0.f;
  const float sc = 0.08838834764831845f;   // 1/sqrt(128)

#pragma unroll
  for (int tile = 0; tile < 2; ++tile) {
    // ---- stage bias tile: 16 rows x 4KB contiguous each ----
#pragma unroll
    for (int r = 0; r < 16; ++r) {
      const float* src = Bh + (size_t)r * T_DIM + tile * 1024 + tid * 4;
      gl_lds16(src, &lds[r * PADW + tid * 4]);
    }
    __syncthreads();   // drains vmcnt -> tile resident
    // ---- each wave: 8 sub-bodies of 32 s, strided by 128 ----
#pragma unroll
    for (int sub = 0; sub < 8; ++sub) {
      int soff = sub * 128 + w * 32;          // offset within tile
      int s0 = tile * 1024 + soff;            // global s
      int s16a = s0 >> 4;
      const u16* ka = Kf + (size_t)s16a * 2048;
      floatx4 st0 = {0.f,0.f,0.f,0.f}, st1 = {0.f,0.f,0.f,0.f};
#pragma unroll
      for (int t = 0; t < 4; ++t) {
        st0 = mfma32(*(const short8*)(ka + t * 512), qf[t], st0);
        st1 = mfma32(*(const short8*)(ka + 2048 + t * 512), qf[t], st1);
      }
      floatx4 b0 = *(const floatx4*)&lds[lq * PADW + soff + lg * 4];
      floatx4 b1 = *(const floatx4*)&lds[lq * PADW + soff + lg * 4 + 16];
      float p[8]; float tmax = -1e30f;
#pragma unroll
      for (int j = 0; j < 4; ++j) {
        p[j]     = st0[j] * sc + b0[j];
        p[4 + j] = st1[j] * sc + b1[j];
        tmax = fmaxf(tmax, fmaxf(p[j], p[4 + j]));
      }
      tmax = fmaxf(tmax, __shfl_xor(tmax, 16));
      tmax = fmaxf(tmax, __shfl_xor(tmax, 32));
      float mn = fmaxf(m, tmax);
      float alpha = __expf(m - mn);
      float rs = 0.f;
      short4v pb0, pb1;
#pragma unroll
      for (int j = 0; j < 4; ++j) {
        float e0 = __expf(p[j] - mn), e1 = __expf(p[4 + j] - mn);
        rs += e0 + e1;
        pb0[j] = (short)f2bf(e0);
        pb1[j] = (short)f2bf(e1);
      }
      rs += __shfl_xor(rs, 16);
      rs += __shfl_xor(rs, 32);
      l = l * alpha + rs; m = mn;
#pragma unroll
      for (int dt = 0; dt < 8; ++dt) o[dt] *= alpha;
      const u16* vb = Vf + (size_t)s16a * 2048;
#pragma unroll
      for (int dp = 0; dp < 4; ++dp) {
        short8 wa = *(const short8*)(vb + dp * 512);
        short8 wb = *(const short8*)(vb + 2048 + dp * 512);
        short4v a0 = {wa[0], wa[1], wa[2], wa[3]};
        short4v a1 = {wa[4], wa[5], wa[6], wa[7]};
        short4v c0 = {wb[0], wb[1], wb[2], wb[3]};
        short4v c1 = {wb[4], wb[5], wb[6], wb[7]};
        o[2*dp]     = mfma16(a0, pb0, o[2*dp]);
        o[2*dp + 1] = mfma16(a1, pb0, o[2*dp + 1]);
        o[2*dp]     = mfma16(c0, pb1, o[2*dp]);
        o[2*dp + 1] = mfma16(c1, pb1, o[2*dp + 1]);
      }
    }
    __syncthreads();   // all waves done reading before restage/merge
  }

  // ---- in-block 4-way (m,l,o) merge via LDS ----
  if (lg == 0) { lds[8448 + w * 16 + lq] = m; lds[8512 + w * 16 + lq] = l; }
  __syncthreads();
  float M = -1e30f;
#pragma unroll
  for (int i = 0; i < 4; ++i) M = fmaxf(M, lds[8448 + i * 16 + lq]);
  float scale = __expf(m - M);
#pragma unroll
  for (int dt = 0; dt < 8; ++dt) {
    floatx4 so = o[dt] * scale;
    *(floatx4*)&lds[w * 2112 + lq * 132 + dt * 16 + lg * 4] = so;
  }
  __syncthreads();
  // final reduce + normalize + write: thread t -> row t>>4, d0 = (t&15)*8
  {
    int row = tid >> 4, d0 = (tid & 15) * 8;
    float M2 = -1e30f;
#pragma unroll
    for (int i = 0; i < 4; ++i) M2 = fmaxf(M2, lds[8448 + i * 16 + row]);
    float den = 0.f;
#pragma unroll
    for (int i = 0; i < 4; ++i)
      den += __expf(lds[8448 + i * 16 + row] - M2) * lds[8512 + i * 16 + row];
    float inv = 1.0f / den;
    short8 ov;
#pragma unroll
    for (int k = 0; k < 8; ++k) {
      float s = 0.f;
#pragma unroll
      for (int i = 0; i < 4; ++i) s += lds[i * 2112 + row * 132 + d0 + k];
      ov[k] = (short)f2bf(s * inv);
    }
    *(short8*)(comb + (size_t)(q0 + row) * NCOL2 + h * HD + d0) = ov;
  }
}

extern "C" void kernel_launch(void* const* d_in, const int* in_sizes, int n_in,
                              void* d_out, int out_size, void* d_ws, size_t ws_size,
                              hipStream_t stream) {
  (void)in_sizes; (void)n_in; (void)out_size; (void)ws_size;
  const float* x     = (const float*)d_in[0];
  const float* ages  = (const float*)d_in[1];
  const float* sinp  = (const float*)d_in[2];
  const float* cosp  = (const float*)d_in[3];
  const float* bias  = (const float*)d_in[4];
  const float* normw = (const float*)d_in[5];
  const float* w_in  = (const float*)d_in[6];
  const float* b_in  = (const float*)d_in[7];
  const float* w_out = (const float*)d_in[8];
  const float* b_out = (const float*)d_in[9];

  char* ws = (char*)d_ws;
  const size_t SZ_XN   = (size_t)T_DIM * H_DIM * 2;      //  8 MiB
  const size_t SZ_W1T  = (size_t)NCOL1 * H_DIM * 2;      //  88 MiB
  const size_t SZ_T    = (size_t)T_DIM * NCOL1 * 2;      //  88 MiB
  const size_t SZ_HEAD = (size_t)NH * T_DIM * HD * 2;    //   8 MiB
  u16* xn   = (u16*)(ws);
  u16* w1t  = (u16*)(ws + SZ_XN);
  u16* tb   = (u16*)(ws + SZ_XN + SZ_W1T);
  u16* qb   = (u16*)(ws + SZ_XN + SZ_W1T + SZ_T);
  u16* kf   = (u16*)(ws + SZ_XN + SZ_W1T + SZ_T + SZ_HEAD);
  u16* vf   = (u16*)(ws + SZ_XN + SZ_W1T + SZ_T + 2 * SZ_HEAD);
  u16* w2t  = (u16*)(ws + SZ_XN);                  // reuse w1t region (dead after GEMM1)
  u16* comb = (u16*)(ws + SZ_XN + (48ull << 20));  // also inside w1t region, disjoint from w2t
  float* part = (float*)tb;                        // split-K partials (64 MiB) in dead tb region

  rmsnorm_k<<<T_DIM, 256, 0, stream>>>(x, ages, normw, xn);
  transpose_f32_bf16<<<dim3(NCOL1 / 32, H_DIM / 32), 256, 0, stream>>>(w_in, w1t, H_DIM, NCOL1);
  gemm256<0><<<(T_DIM / 256) * (NCOL1 / 256), 512, 0, stream>>>(
      xn, w1t, b_in, tb, T_DIM, NCOL1, H_DIM, H_DIM);
  rope_split<<<dim3(T_DIM / 32, NH), 256, 0, stream>>>(tb, sinp, cosp, qb, kf, vf);
  silu_mul<<<(T_DIM * I_DIM) / (256 * 8), 256, 0, stream>>>(tb, comb);
  transpose_f32_bf16<<<dim3(H_DIM / 32, NCOL2 / 32), 256, 0, stream>>>(w_out, w2t, NCOL2, H_DIM);
  attn_fused<<<NH * (T_DIM / 16), 256, 0, stream>>>(qb, kf, vf, bias, comb);
  gemm256<2><<<(T_DIM / 256) * (H_DIM / 256) * KSPLIT, 512, 0, stream>>>(
      comb, w2t, b_out, part, T_DIM, H_DIM, NCOL2, KSLEN);
  reduce_split<<<(T_DIM * H_DIM / 4) / 256, 256, 0, stream>>>(part, b_out, (float*)d_out);
}